// Round 7
// baseline (401.124 us; speedup 1.0000x reference)
//
#include <hip/hip_runtime.h>
#include <hip/hip_bf16.h>
#include <cstdint>

typedef __attribute__((ext_vector_type(8))) short short8;
typedef __attribute__((ext_vector_type(4))) float floatx4;

#define NC   5
#define PP   196
#define DD   384
#define MM   512
#define ROWS (MM * PP)     /* 100352 = 1568 * 64 exactly */
#define NRB  1568
#define BR   64            /* rows per block */
#define EPSN 1e-12f

/* unified column space: 980 real cols padded to 1024 = 8 tile-PAIRS of 128 cols.
   cols >= 980 replicate col 979 (max-invariant). snw layout = sequence of 96
   8KB blocks (one per (gp,kk)), each block EXACTLY the LDS image consumed by
   the K-step: [ctg 8][lane 64][16B]; lane holds col = gp*128 + ctg*16 + (l&15),
   k = kk*32 + (l>>4)*8 + e. Staged via global_load_lds (wave-uniform LDS dest
   + lane*16; per-lane global src = pre-swizzled). */
#define NGP        8
#define KSTEPS     96          /* 8 gp * 12 kk */
#define BLK_BYTES  8192

/* monotone float <-> uint encoding so atomicMax(unsigned) orders like float */
__device__ __forceinline__ unsigned enc_f(float f) {
    unsigned u = __float_as_uint(f);
    return (u & 0x80000000u) ? ~u : (u | 0x80000000u);
}
__device__ __forceinline__ float dec_f(unsigned u) {
    unsigned b = (u & 0x80000000u) ? (u ^ 0x80000000u) : ~u;
    return __uint_as_float(b);
}
#define ENC_NEG_INF 0x007FFFFFu

__device__ __forceinline__ int cls_of(int col) {
    return (col >= 784) ? 4 : (col >= 588) ? 3 : (col >= 392) ? 2 : (col >= 196) ? 1 : 0;
}

typedef __attribute__((address_space(1))) const unsigned int gu32;
typedef __attribute__((address_space(3))) unsigned int lu32;
#define GL2LDS(g, l) __builtin_amdgcn_global_load_lds((gu32*)(g), (lu32*)(l), 16, 0, 0)

/* ---- pass 1a: 1/||support_row|| (980 rows) ---- */
__global__ __launch_bounds__(256) void k_norm0(const float* __restrict__ sup,
                                               float* __restrict__ sinv) {
    int wid = threadIdx.x >> 6, lane = threadIdx.x & 63;
    int r = blockIdx.x * 4 + wid;
    if (r >= NC * PP) return;
    const float* src = sup + (size_t)r * DD;
    float s = 0.f;
    #pragma unroll
    for (int j = 0; j < 6; ++j) { float v = src[lane + j * 64]; s += v * v; }
    #pragma unroll
    for (int off = 1; off < 64; off <<= 1) s += __shfl_xor(s, off, 64);
    if (lane == 0) sinv[r] = 1.0f / fmaxf(sqrtf(s), EPSN);
}

/* ---- pass 1b: normalize + swizzle support into the staged-block layout.
        slice s (16B): l = s&63, ctg = (s>>6)&7, t = s>>9 (0..95, = gp*12+kk). ---- */
__global__ __launch_bounds__(256) void k_swz(const float* __restrict__ sup,
                                             const float* __restrict__ sinv,
                                             __hip_bfloat16* __restrict__ snw) {
    int s = blockIdx.x * 256 + threadIdx.x;       /* 49152 slices of 16 B */
    int l   = s & 63;
    int ctg = (s >> 6) & 7;
    int t   = s >> 9;                              /* 0..95 */
    int kk  = t % 12;
    int gp  = t / 12;
    int col = gp * 128 + ctg * 16 + (l & 15);
    if (col > NC * PP - 1) col = NC * PP - 1;      /* replicate last col: max-invariant */
    const float* sp = sup + (size_t)col * DD + kk * 32 + (l >> 4) * 8;
    float inv = sinv[col];
    alignas(16) __hip_bfloat16 hb[8];
    #pragma unroll
    for (int e = 0; e < 8; ++e) hb[e] = __float2bfloat16(sp[e] * inv);
    *(uint4*)((char*)snw + (size_t)s * 16) = *(const uint4*)hb;
}

/* ---- main: one block per 64-row strip. R7 = structural change: B staged
        COOPERATIVELY into LDS via global_load_lds, double-buffered, ONE
        barrier per K-step (m97 pattern, HW-verified ~36% of peak). R2-R6
        post-mortems: the per-wave register-B pipeline pins MfmaUtil at ~26%
        regardless of occupancy (26/39/49%), conflicts (4.2M/0), a-dbuf, or
        traffic (1.2/2.4GB); every depth increase past 2 spills (R4, R6).
        Here pipeline depth lives in LDS, not VGPRs. Block processes 128-col
        tile-pairs so each wave owns 8 independent acc chains (2ct x 4rt;
        R1: 4 chains stalls the MFMA pipe). A staged conflict-free
        (slot==lane, R4/R5-verified 0 conflicts). Swapped operands: col-max
        = 3 fmax + 2 shfl per frag. LDS 66KB -> 2 blocks/CU (expected
        occupancy ~25%: by design, barrier pipeline hides latency). ---- */
__global__ __launch_bounds__(256, 2) void k_gemm_max(const float* __restrict__ q,
                                                     const __hip_bfloat16* __restrict__ snw,
                                                     float* __restrict__ rowmaxg) {
    /* A fragment order: [kk 12][rt 4][lane 64][8 bf16] = 49152 B */
    __shared__ __align__(16) __hip_bfloat16 As[12 * 4 * 64 * 8];
    __shared__ __align__(16) __hip_bfloat16 Bb[2 * 4096];   /* 2 x 8KB staged B */
    __shared__ unsigned rmax[BR * NC];
    __shared__ float rss[BR];

    const int tid  = threadIdx.x;
    const int row0 = blockIdx.x * BR;
    const int lane = tid & 63;
    const int wav  = tid >> 6;

    char* Bbc = (char*)Bb;
    const char* snwb = (const char*)snw;

    for (int i = tid; i < BR * NC; i += 256) rmax[i] = ENC_NEG_INF;

    /* prologue: stage K-step 0 into buf 0 (fire-and-forget; drained by the
       barrier below). Wave w stages chunks w and w+4 of the 8KB block. */
    {
        const char* gs = snwb + (size_t)wav * 1024 + (size_t)lane * 16;
        char* ld = Bbc + wav * 1024;
        GL2LDS(gs, ld);
        GL2LDS(gs + 4096, ld + 4096);
    }

    /* ---- A staging: wave w = rt group (rows w*16..+15); lane: c16 = row,
            quad = k-subchunk. Write slot == lane -> contiguous 1KB
            ds_write_b128 bursts (conflict-free; R4/R5-verified). Fused
            full-K row sumsq. Non-temporal: query must not evict B from L2. */
    {
        const int c16  = lane & 15;
        const int quad = lane >> 4;
        const int arow = wav * 16 + c16;
        const float* src = q + (size_t)(row0 + arow) * DD + quad * 8;
        float ss = 0.f;
        #pragma unroll
        for (int i = 0; i < 12; ++i) {
            const floatx4* p = (const floatx4*)(src + i * 32);
            floatx4 x0 = __builtin_nontemporal_load(p);
            floatx4 x1 = __builtin_nontemporal_load(p + 1);
            ss += x0.x*x0.x + x0.y*x0.y + x0.z*x0.z + x0.w*x0.w
                + x1.x*x1.x + x1.y*x1.y + x1.z*x1.z + x1.w*x1.w;
            alignas(16) __hip_bfloat16 hb[8];
            hb[0] = __float2bfloat16(x0.x); hb[1] = __float2bfloat16(x0.y);
            hb[2] = __float2bfloat16(x0.z); hb[3] = __float2bfloat16(x0.w);
            hb[4] = __float2bfloat16(x1.x); hb[5] = __float2bfloat16(x1.y);
            hb[6] = __float2bfloat16(x1.z); hb[7] = __float2bfloat16(x1.w);
            *(uint4*)&As[((i * 4 + wav) * 64 + lane) * 8] = *(const uint4*)hb;
        }
        ss += __shfl_xor(ss, 16, 64);
        ss += __shfl_xor(ss, 32, 64);
        if (quad == 0) rss[arow] = ss;
    }

    __syncthreads();    /* A staged + K-step 0 B landed (full vmcnt/lgkm drain) */

    size_t gnext = BLK_BYTES;                      /* byte offset of K-step t+1 */
    int cur = 0;
    const int ctg0 = 2 * wav;                      /* wave's two 16-col frags */

    #pragma unroll 1
    for (int gp = 0; gp < NGP; ++gp) {
        floatx4 acc[2][4];
        #pragma unroll
        for (int i = 0; i < 2; ++i)
            #pragma unroll
            for (int j = 0; j < 4; ++j) acc[i][j] = (floatx4){0.f, 0.f, 0.f, 0.f};

        #pragma unroll 1
        for (int kk = 0; kk < 12; ++kk) {
            /* stage K-step t+1 into the other buffer (overlaps this step's
               ds_read + MFMA; completion guaranteed by end-of-step barrier) */
            if (gnext < (size_t)KSTEPS * BLK_BYTES) {
                const char* gs = snwb + gnext + (size_t)wav * 1024 + (size_t)lane * 16;
                char* ld = Bbc + (cur ^ 1) * BLK_BYTES + wav * 1024;
                GL2LDS(gs, ld);
                GL2LDS(gs + 4096, ld + 4096);
            }

            /* B frags from LDS (contiguous ds_read_b128), A frags, 8 MFMAs
               (8 independent chains). Swapped operands: first arg = support. */
            const char* bptr = Bbc + cur * BLK_BYTES + ctg0 * 1024 + lane * 16;
            short8 bf0 = *(const short8*)bptr;
            short8 bf1 = *(const short8*)(bptr + 1024);
            short8 af[4];
            #pragma unroll
            for (int rt = 0; rt < 4; ++rt)
                af[rt] = *(const short8*)&As[((kk * 4 + rt) * 64 + lane) * 8];
            #pragma unroll
            for (int rt = 0; rt < 4; ++rt) {
                acc[0][rt] = __builtin_amdgcn_mfma_f32_16x16x32_bf16(bf0, af[rt], acc[0][rt], 0, 0, 0);
                acc[1][rt] = __builtin_amdgcn_mfma_f32_16x16x32_bf16(bf1, af[rt], acc[1][rt], 0, 0, 0);
            }

            __syncthreads();                       /* the ONE barrier per K-step */
            cur ^= 1;
            gnext += BLK_BYTES;
        }

        /* ---- epilogue (between barriers; LDS-atomic only, no Bb access).
                Swapped C layout: D row (support col) = gp*128 + ctg*16 +
                (lane>>4)*4 + reg; D col (query row) = rt*16 + (lane&15). ---- */
        {
            const int quad = lane >> 4;
            #pragma unroll
            for (int ci = 0; ci < 2; ++ci) {
                const int cb  = gp * 128 + (ctg0 + ci) * 16;
                const int clo = cls_of(cb), chi = cls_of(cb + 15);
                if (clo == chi) {                  /* common: single class */
                    #pragma unroll
                    for (int rt = 0; rt < 4; ++rt) {
                        float mx = fmaxf(fmaxf(acc[ci][rt][0], acc[ci][rt][1]),
                                         fmaxf(acc[ci][rt][2], acc[ci][rt][3]));
                        mx = fmaxf(mx, __shfl_xor(mx, 16, 64));
                        mx = fmaxf(mx, __shfl_xor(mx, 32, 64));
                        if (lane < 16) atomicMax(&rmax[(rt * 16 + lane) * NC + clo], enc_f(mx));
                    }
                } else {                           /* boundary cuts inside frag */
                    const int bnd = chi * PP;
                    #pragma unroll
                    for (int rt = 0; rt < 4; ++rt) {
                        float mlo = -INFINITY, mhi = -INFINITY;
                        #pragma unroll
                        for (int reg = 0; reg < 4; ++reg) {
                            int scol = cb + quad * 4 + reg;
                            if (scol >= bnd) mhi = fmaxf(mhi, acc[ci][rt][reg]);
                            else             mlo = fmaxf(mlo, acc[ci][rt][reg]);
                        }
                        mlo = fmaxf(mlo, __shfl_xor(mlo, 16, 64));
                        mlo = fmaxf(mlo, __shfl_xor(mlo, 32, 64));
                        mhi = fmaxf(mhi, __shfl_xor(mhi, 16, 64));
                        mhi = fmaxf(mhi, __shfl_xor(mhi, 32, 64));
                        if (lane < 16) {
                            atomicMax(&rmax[(rt * 16 + lane) * NC + clo], enc_f(mlo));
                            atomicMax(&rmax[(rt * 16 + lane) * NC + chi], enc_f(mhi));
                        }
                    }
                }
            }
        }
    }

    __syncthreads();
    /* rowmaxg layout [c][row] -> coalesced stores here, coalesced loads in k_top6 */
    for (int i = tid; i < BR * NC; i += 256) {
        int c = i >> 6, row = i & 63;
        float inv = 1.0f / fmaxf(sqrtf(rss[row]), EPSN);
        __builtin_nontemporal_store(dec_f(rmax[row * NC + c]) * inv,
                                    &rowmaxg[(size_t)c * ROWS + row0 + row]);
    }
}

/* ---- top-6 sum per (m, c): one wave each ---- */
__global__ __launch_bounds__(256) void k_top6(const float* __restrict__ rowmaxg,
                                              const float* __restrict__ scale,
                                              const float* __restrict__ bias,
                                              float* __restrict__ out) {
    int wav = threadIdx.x >> 6, lane = threadIdx.x & 63;
    int pair = blockIdx.x * 4 + wav;
    if (pair >= MM * NC) return;
    int m = pair / NC, c = pair % NC;
    size_t base = (size_t)c * ROWS + (size_t)m * PP;
    float v[4];
    #pragma unroll
    for (int i = 0; i < 4; ++i) {
        int p = lane + i * 64;
        v[i] = (p < PP) ? rowmaxg[base + p] : -INFINITY;
    }
    float sum = 0.f;
    for (int t = 0; t < 6; ++t) {
        float bv = v[0]; int bi = 0;
        #pragma unroll
        for (int i = 1; i < 4; ++i) { if (v[i] > bv) { bv = v[i]; bi = i; } }
        int gid = bi * 64 + lane;
        #pragma unroll
        for (int off = 1; off < 64; off <<= 1) {
            float ov = __shfl_xor(bv, off, 64);
            int og  = __shfl_xor(gid, off, 64);
            if (ov > bv || (ov == bv && og < gid)) { bv = ov; gid = og; }
        }
        sum += bv;
        if ((gid & 63) == lane) v[gid >> 6] = -INFINITY;  /* kill exactly one */
    }
    if (lane == 0) out[pair] = scale[0] * (sum + bias[0]);
}

extern "C" void kernel_launch(void* const* d_in, const int* in_sizes, int n_in,
                              void* d_out, int out_size, void* d_ws, size_t ws_size,
                              hipStream_t stream) {
    const float* support = (const float*)d_in[0];
    const float* query   = (const float*)d_in[1];
    const float* scale   = (const float*)d_in[2];
    const float* bias    = (const float*)d_in[3];
    float* out = (float*)d_out;

    char* ws = (char*)d_ws;
    __hip_bfloat16* snw = (__hip_bfloat16*)ws;             /* 96*8192 = 786432 B */
    float* sinv         = (float*)(ws + 786432);           /* 980*4 -> pad to 4096 */
    float* rowmaxg      = (float*)(ws + 786432 + 4096);    /* 5*100352*4 = 2007040 */

    hipLaunchKernelGGL(k_norm0,   dim3(245),  dim3(256), 0, stream, support, sinv);
    hipLaunchKernelGGL(k_swz,     dim3(192),  dim3(256), 0, stream, support, sinv, snw);
    hipLaunchKernelGGL(k_gemm_max,dim3(NRB),  dim3(256), 0, stream, query, snw, rowmaxg);
    hipLaunchKernelGGL(k_top6,    dim3(640),  dim3(256), 0, stream, rowmaxg, scale, bias, out);
}

// Round 8
// 397.313 us; speedup vs baseline: 1.0096x; 1.0096x over previous
//
#include <hip/hip_runtime.h>
#include <hip/hip_bf16.h>
#include <cstdint>

typedef __attribute__((ext_vector_type(8))) short short8;
typedef __attribute__((ext_vector_type(4))) float floatx4;

#define NC   5
#define PP   196
#define DD   384
#define MM   512
#define ROWS (MM * PP)     /* 100352 = 1568 * 64 exactly */
#define NRB  1568
#define BR   64
#define EPSN 1e-12f

/* unified column space: 980 cols padded to 1024 = 16 tiles x 64; wave w owns
   tiles g = w + 4*ti (ti 0..3). snw layout: PER-WAVE LINEAR B STREAM:
   [w 4][f 48][4KB] (+4 slack blocks/wave, read-only garbage for tail
   prefetch -> every refill is branchless: addr = wbase + (f+4)*4096).
   4KB kstep block: [ct 4][lane 64][16B]; lane = quad*16+c16 holds
   col = g*64 + ct*16 + c16, k = kk*32 + quad*8 + e. */
#define NTILES     16
#define JBLK       52                 /* 48 real + 4 slack */
#define WBLK       (JBLK * 4096)      /* 212992 B per wave */

/* monotone float <-> uint encoding so atomicMax(unsigned) orders like float */
__device__ __forceinline__ unsigned enc_f(float f) {
    unsigned u = __float_as_uint(f);
    return (u & 0x80000000u) ? ~u : (u | 0x80000000u);
}
__device__ __forceinline__ float dec_f(unsigned u) {
    unsigned b = (u & 0x80000000u) ? (u ^ 0x80000000u) : ~u;
    return __uint_as_float(b);
}
#define ENC_NEG_INF 0x007FFFFFu

__device__ __forceinline__ int cls_of(int col) {
    return (col >= 784) ? 4 : (col >= 588) ? 3 : (col >= 392) ? 2 : (col >= 196) ? 1 : 0;
}

/* ---- pass 1 (fused): per-col L2 norm + swizzle into per-wave linear stream.
        One wave per support col (980 = 245 blocks x 4 waves). ---- */
__global__ __launch_bounds__(256) void k_prep(const float* __restrict__ sup,
                                              __hip_bfloat16* __restrict__ snw) {
    __shared__ float colbuf[4][DD];
    int wid = threadIdx.x >> 6, lane = threadIdx.x & 63;
    int col = blockIdx.x * 4 + wid;               /* 0..979, exact */
    const float* src = sup + (size_t)col * DD;
    float ss = 0.f;
    #pragma unroll
    for (int j = 0; j < 6; ++j) {
        float v = src[lane + j * 64];
        ss += v * v;
        colbuf[wid][lane + j * 64] = v;
    }
    #pragma unroll
    for (int off = 1; off < 64; off <<= 1) ss += __shfl_xor(ss, off, 64);
    float inv = 1.0f / fmaxf(sqrtf(ss), EPSN);
    /* lanes 0..47 each emit one 16B slice: kk = lane>>2, quad = lane&3 */
    if (lane < 48) {
        int kk = lane >> 2, quad = lane & 3;
        const float* cb = colbuf[wid] + kk * 32 + quad * 8;
        alignas(16) __hip_bfloat16 hb[8];
        #pragma unroll
        for (int e = 0; e < 8; ++e) hb[e] = __float2bfloat16(cb[e] * inv);
        int g = col >> 6, loc = col & 63, ct = loc >> 4, c16 = loc & 15;
        int w = g & 3, ti = g >> 2, j = ti * 12 + kk;
        size_t off = ((size_t)(w * JBLK + j) * 256 + ct * 64 + quad * 16 + c16) * 16;
        *(uint4*)((char*)snw + off) = *(const uint4*)hb;
    }
    /* cols 960..979 replicate into the pad cols 980..1023: tiles 15 (w3,ti3)
       cover cols 960..1023; pad cols must hold a valid replica (max-invariant).
       Col 979 additionally fills 980..1023's slots. */
    if (col == NC * PP - 1 && lane < 48) {
        int kk = lane >> 2, quad = lane & 3;
        const float* cb = colbuf[wid] + kk * 32 + quad * 8;
        alignas(16) __hip_bfloat16 hb[8];
        #pragma unroll
        for (int e = 0; e < 8; ++e) hb[e] = __float2bfloat16(cb[e] * inv);
        for (int pc = NC * PP; pc < 1024; ++pc) {
            int g = pc >> 6, loc = pc & 63, ct = loc >> 4, c16 = loc & 15;
            int w = g & 3, ti = g >> 2, j = ti * 12 + kk;
            size_t off = ((size_t)(w * JBLK + j) * 256 + ct * 64 + quad * 16 + c16) * 16;
            *(uint4*)((char*)snw + off) = *(const uint4*)hb;
        }
    }
}

/* ---- main: one block per 64-row strip. R8 theory: R3/R5/R7 all spend
        ~1300-2000cy per kstep (~150cy of work) because every B refill sat
        under `if (nk<12) else if (g+4<NTILES)` -> compiler can't count
        outstanding loads -> conservative vmcnt drain before each use
        (real matrix-pipe occupancy ~7%; MfmaUtil's 26% is a 16cy/MFMA
        convention artifact). Fix: per-wave LINEAR B stream + slack tail ->
        every refill unconditional; 12 ksteps fully unrolled (period-4,
        depth-4) -> straight-line body -> static vmcnt(12), load-to-use =
        3 ksteps. BR=64: B traffic 1.2GB (BR=32's 2.4GB @ ~19TB/s floors at
        ~126us = R3/R5's exact time). Regs: b64+a32+acc64 ~ 184 < 256 ->
        2 waves/SIMD, no spill (R4/R6 lesson: watch WRITE_SIZE).
        A staged conflict-free (slot==lane, 0-conflict verified). Swapped
        operands -> col-max = 15 fmax + 2 shfl. NO main-loop barriers. ---- */
__global__ __launch_bounds__(256, 2) void k_gemm_max(const float* __restrict__ q,
                                                     const __hip_bfloat16* __restrict__ snw,
                                                     float* __restrict__ rowmaxg) {
    /* As fragment order: [kk 12][rt 4][lane 64][8 bf16] = 49152 B */
    __shared__ __align__(16) __hip_bfloat16 As[12 * 4 * 64 * 8];
    __shared__ unsigned rmax[BR * NC];
    __shared__ float rss[BR];

    const int tid  = threadIdx.x;
    const int row0 = blockIdx.x * BR;
    const int lane = tid & 63;
    const int wav  = tid >> 6;

    for (int i = tid; i < BR * NC; i += 256) rmax[i] = ENC_NEG_INF;

    /* ---- A staging: wave w = rt (rows w*16..+15); write slot == lane ->
            contiguous 1KB ds_write_b128 bursts (verified 0 conflicts).
            Fused full-K row sumsq. Non-temporal: don't evict B from L2. */
    {
        const int c16  = lane & 15;
        const int quad = lane >> 4;
        const int arow = wav * 16 + c16;
        const float* src = q + (size_t)(row0 + arow) * DD + quad * 8;
        float ss = 0.f;
        #pragma unroll
        for (int i = 0; i < 12; ++i) {
            const floatx4* p = (const floatx4*)(src + i * 32);
            floatx4 x0 = __builtin_nontemporal_load(p);
            floatx4 x1 = __builtin_nontemporal_load(p + 1);
            ss += x0.x*x0.x + x0.y*x0.y + x0.z*x0.z + x0.w*x0.w
                + x1.x*x1.x + x1.y*x1.y + x1.z*x1.z + x1.w*x1.w;
            alignas(16) __hip_bfloat16 hb[8];
            hb[0] = __float2bfloat16(x0.x); hb[1] = __float2bfloat16(x0.y);
            hb[2] = __float2bfloat16(x0.z); hb[3] = __float2bfloat16(x0.w);
            hb[4] = __float2bfloat16(x1.x); hb[5] = __float2bfloat16(x1.y);
            hb[6] = __float2bfloat16(x1.z); hb[7] = __float2bfloat16(x1.w);
            *(uint4*)&As[((i * 4 + wav) * 64 + lane) * 8] = *(const uint4*)hb;
        }
        ss += __shfl_xor(ss, 16, 64);
        ss += __shfl_xor(ss, 32, 64);
        if (quad == 0) rss[arow] = ss;
    }

    const char* wb = (const char*)snw + (size_t)wav * WBLK + (size_t)lane * 16;
    short8 b0[4], b1[4], b2[4], b3[4], a[2][4];

    /* prologue B prefetch f=0..3 (drained by the barrier) */
    #pragma unroll
    for (int ct = 0; ct < 4; ++ct) b0[ct] = *(const short8*)(wb + 0 * 4096 + ct * 1024);
    #pragma unroll
    for (int ct = 0; ct < 4; ++ct) b1[ct] = *(const short8*)(wb + 1 * 4096 + ct * 1024);
    #pragma unroll
    for (int ct = 0; ct < 4; ++ct) b2[ct] = *(const short8*)(wb + 2 * 4096 + ct * 1024);
    #pragma unroll
    for (int ct = 0; ct < 4; ++ct) b3[ct] = *(const short8*)(wb + 3 * 4096 + ct * 1024);

    __syncthreads();                            /* the ONLY barrier before the end */

    #define AFETCH(pre, kkn)                                                         \
        do { _Pragma("unroll")                                                       \
            for (int rt = 0; rt < 4; ++rt)                                           \
                a[pre][rt] = *(const short8*)&As[(((kkn) * 4 + rt) * 64 + lane) * 8];\
        } while (0)

    #define MFMAS(use, buf)                                                          \
        do { _Pragma("unroll")                                                       \
            for (int ct = 0; ct < 4; ++ct)                                           \
                _Pragma("unroll")                                                    \
                for (int rt = 0; rt < 4; ++rt)                                       \
                    acc[ct][rt] = __builtin_amdgcn_mfma_f32_16x16x32_bf16(           \
                        buf[ct], a[use][rt], acc[ct][rt], 0, 0, 0);                  \
        } while (0)

    /* position p (kk=p): prefetch a for kk=p+1 (wrapping to 0 at 12),
       16 MFMAs on b[p&3], branchless refill of b[p&3] from f = ti*12+p+4. */
    #define POS(p, buf)                                                              \
        do {                                                                         \
            AFETCH((p + 1) & 1, ((p) + 1 < 12) ? (p) + 1 : 0);                       \
            MFMAS((p) & 1, buf);                                                     \
            _Pragma("unroll")                                                        \
            for (int ct = 0; ct < 4; ++ct)                                           \
                buf[ct] = *(const short8*)(bptr + ((p) + 4) * 4096 + ct * 1024);     \
        } while (0)

    AFETCH(0, 0);

    const char* bptr = wb;
    #pragma unroll 1
    for (int ti = 0; ti < 4; ++ti) {
        floatx4 acc[4][4];
        #pragma unroll
        for (int i = 0; i < 4; ++i)
            #pragma unroll
            for (int j = 0; j < 4; ++j) acc[i][j] = (floatx4){0.f, 0.f, 0.f, 0.f};

        POS(0,  b0); POS(1,  b1); POS(2,  b2); POS(3,  b3);
        POS(4,  b0); POS(5,  b1); POS(6,  b2); POS(7,  b3);
        POS(8,  b0); POS(9,  b1); POS(10, b2); POS(11, b3);

        /* ---- epilogue: per-class col-max. Swapped C layout:
                D row (support col) = g*64 + ct*16 + quad*4 + reg,
                D col (query row)   = rt*16 + (lane&15);  g = wav + 4*ti.
                Boundary tiles (g=3,6,9,12): exactly one per wave. ---- */
        {
            const int g = wav + 4 * ti;
            const int colbase = g * 64;
            int ce = colbase + 63; if (ce > NC * PP - 1) ce = NC * PP - 1;
            const int clo = cls_of(colbase), chi = cls_of(ce);
            const int quad = lane >> 4;
            if (clo == chi) {
                #pragma unroll
                for (int rt = 0; rt < 4; ++rt) {
                    float mx = acc[0][rt][0];
                    #pragma unroll
                    for (int ct = 0; ct < 4; ++ct)
                        #pragma unroll
                        for (int reg = 0; reg < 4; ++reg)
                            if (ct | reg) mx = fmaxf(mx, acc[ct][rt][reg]);
                    mx = fmaxf(mx, __shfl_xor(mx, 16, 64));
                    mx = fmaxf(mx, __shfl_xor(mx, 32, 64));
                    if (lane < 16) atomicMax(&rmax[(rt * 16 + lane) * NC + clo], enc_f(mx));
                }
            } else {
                const int bnd = chi * PP;
                #pragma unroll
                for (int rt = 0; rt < 4; ++rt) {
                    float mlo = -INFINITY, mhi = -INFINITY;
                    #pragma unroll
                    for (int ct = 0; ct < 4; ++ct)
                        #pragma unroll
                        for (int reg = 0; reg < 4; ++reg) {
                            int scol = colbase + ct * 16 + quad * 4 + reg;
                            if (scol >= bnd) mhi = fmaxf(mhi, acc[ct][rt][reg]);
                            else             mlo = fmaxf(mlo, acc[ct][rt][reg]);
                        }
                    mlo = fmaxf(mlo, __shfl_xor(mlo, 16, 64));
                    mlo = fmaxf(mlo, __shfl_xor(mlo, 32, 64));
                    mhi = fmaxf(mhi, __shfl_xor(mhi, 16, 64));
                    mhi = fmaxf(mhi, __shfl_xor(mhi, 32, 64));
                    if (lane < 16) {
                        atomicMax(&rmax[(rt * 16 + lane) * NC + clo], enc_f(mlo));
                        atomicMax(&rmax[(rt * 16 + lane) * NC + chi], enc_f(mhi));
                    }
                }
            }
        }
        bptr += 12 * 4096;
    }

    __syncthreads();
    /* rowmaxg layout [c][row] -> coalesced stores here, coalesced loads in k_top6 */
    for (int i = tid; i < BR * NC; i += 256) {
        int c = i >> 6, row = i & 63;
        float inv = 1.0f / fmaxf(sqrtf(rss[row]), EPSN);
        __builtin_nontemporal_store(dec_f(rmax[row * NC + c]) * inv,
                                    &rowmaxg[(size_t)c * ROWS + row0 + row]);
    }
}

/* ---- top-6 sum per (m, c): one wave each ---- */
__global__ __launch_bounds__(256) void k_top6(const float* __restrict__ rowmaxg,
                                              const float* __restrict__ scale,
                                              const float* __restrict__ bias,
                                              float* __restrict__ out) {
    int wav = threadIdx.x >> 6, lane = threadIdx.x & 63;
    int pair = blockIdx.x * 4 + wav;
    if (pair >= MM * NC) return;
    int m = pair / NC, c = pair % NC;
    size_t base = (size_t)c * ROWS + (size_t)m * PP;
    float v[4];
    #pragma unroll
    for (int i = 0; i < 4; ++i) {
        int p = lane + i * 64;
        v[i] = (p < PP) ? rowmaxg[base + p] : -INFINITY;
    }
    float sum = 0.f;
    for (int t = 0; t < 6; ++t) {
        float bv = v[0]; int bi = 0;
        #pragma unroll
        for (int i = 1; i < 4; ++i) { if (v[i] > bv) { bv = v[i]; bi = i; } }
        int gid = bi * 64 + lane;
        #pragma unroll
        for (int off = 1; off < 64; off <<= 1) {
            float ov = __shfl_xor(bv, off, 64);
            int og  = __shfl_xor(gid, off, 64);
            if (ov > bv || (ov == bv && og < gid)) { bv = ov; gid = og; }
        }
        sum += bv;
        if ((gid & 63) == lane) v[gid >> 6] = -INFINITY;  /* kill exactly one */
    }
    if (lane == 0) out[pair] = scale[0] * (sum + bias[0]);
}

extern "C" void kernel_launch(void* const* d_in, const int* in_sizes, int n_in,
                              void* d_out, int out_size, void* d_ws, size_t ws_size,
                              hipStream_t stream) {
    const float* support = (const float*)d_in[0];
    const float* query   = (const float*)d_in[1];
    const float* scale   = (const float*)d_in[2];
    const float* bias    = (const float*)d_in[3];
    float* out = (float*)d_out;

    char* ws = (char*)d_ws;
    __hip_bfloat16* snw = (__hip_bfloat16*)ws;             /* 4*212992 = 851968 B */
    float* rowmaxg      = (float*)(ws + 860160);           /* 5*100352*4 = 2007040 */

    hipLaunchKernelGGL(k_prep,    dim3(245),  dim3(256), 0, stream, support, snw);
    hipLaunchKernelGGL(k_gemm_max,dim3(NRB),  dim3(256), 0, stream, query, snw, rowmaxg);
    hipLaunchKernelGGL(k_top6,    dim3(640),  dim3(256), 0, stream, rowmaxg, scale, bias, out);
}